// Round 12
// baseline (130.231 us; speedup 1.0000x reference)
//
#include <hip/hip_runtime.h>

// multi_triples_lstm v12: two chains per WG — amortize the per-step round cost.
// Grid 1024 x 256 thr. WG owns chains A,B (16 batches each). Wave w computes
// unit-quarter w for BOTH chains each iteration: 4 h-MFMA + 2x activations +
// 2 ds_write + ONE barrier + 2 ds_read_b128 + 4 x-MFMA. Round retires 2
// chain-steps (vs 1 in v10) at the same per-CU issue content; the two chains'
// dependency ladders interleave within each wave (ILP).
// Shared-denominator algebra (7 trans/unit-step), packed f32x2 full-rate,
// cvt_pkrtz h-pack; scales folded into fp16 weights (i/f/o * -log2e, g * +2log2e).
//
// LDS (dynamic):
//   XA  @ 0     : 16 rows x 1040B (chain A fp16 feats; (b,t) at b*1040+t*32)
//   XB  @ 16640 : 16 rows x 1040B (chain B)
//   HX0 @ 33280 : 2048B (A: 64 lanes x 16B @ +0, B: @ +1024)
//   HX1 @ 35328 : 2048B (double buffer)
//   Z   @ 37376 : 32B zeros (x-frag quads 2,3)
//   fc2 scratch overlays X (2 chains x 16 rows x 144B)
#define LDS_BYTES 37408

typedef _Float16 f16x8 __attribute__((ext_vector_type(8)));
typedef __fp16   fp16x2 __attribute__((ext_vector_type(2)));
typedef float    f32x4 __attribute__((ext_vector_type(4)));
typedef float    f32x2 __attribute__((ext_vector_type(2)));

#define LOG2E     1.44269504088896f
#define TWO_LOG2E 2.88539008177793f

__global__ __launch_bounds__(256, 4)
void lstm_fused(const int* __restrict__ objs,
                const float* __restrict__ boxes,
                const int* __restrict__ preds,
                const int* __restrict__ subj,
                const float* __restrict__ obj_emb,
                const float* __restrict__ pred_emb,
                const float* __restrict__ W_ih,
                const float* __restrict__ W_hh,
                const float* __restrict__ b_ih,
                const float* __restrict__ b_hh,
                const float* __restrict__ fc2_W,
                const float* __restrict__ fc2_b,
                float* __restrict__ out)
{
    extern __shared__ char smem[];
    const int tid  = threadIdx.x;
    const int lane = tid & 63;
    const int wv   = tid >> 6;           // 0..3: unit-pair quarter
    const int quad = lane >> 4;          // 0..3
    const int cidx = lane & 15;          // batch index
    const int HXB = 33280, ZOFF = 37376;

    if (tid < 8) ((int*)(smem + ZOFF))[tid] = 0;

    // ---- stage x features (fp16): 2 chains x 16 b x 32 t, 4 t per thread ----
    {
        int row = tid >> 3;              // 0..31 = ch*16 + b
        int t0  = (tid & 7) << 2;        // 0,4,...,28
        long gb = (long)blockIdx.x * 32 + row;
        int4 ov = *(const int4*)(objs  + gb * 32 + t0);
        int4 pv = *(const int4*)(preds + gb * 32 + t0);
        int4 sv = *(const int4*)(subj  + gb * 32 + t0);
        int oarr[4] = {ov.x, ov.y, ov.z, ov.w};
        int parr[4] = {pv.x, pv.y, pv.z, pv.w};
        int sarr[4] = {sv.x, sv.y, sv.z, sv.w};
        char* base = smem + row * 1040;  // ch*16640 + b*1040 == row*1040
        #pragma unroll
        for (int tt = 0; tt < 4; ++tt) {
            int t = t0 + tt;
            const float* eo = obj_emb  + oarr[tt] * 5;
            const float* ep = pred_emb + parr[tt] * 5;
            float4 bx = *(const float4*)(boxes + (gb * 32 + t) * 4);
            f16x8 lo, hi;
            lo[0]=(_Float16)eo[0]; lo[1]=(_Float16)eo[1]; lo[2]=(_Float16)eo[2];
            lo[3]=(_Float16)eo[3]; lo[4]=(_Float16)eo[4];
            lo[5]=(_Float16)ep[0]; lo[6]=(_Float16)ep[1]; lo[7]=(_Float16)ep[2];
            hi[0]=(_Float16)ep[3]; hi[1]=(_Float16)ep[4];
            hi[2]=(_Float16)(sarr[tt]==0 ? 1.0f : 0.0f);
            hi[3]=(_Float16)(sarr[tt]==1 ? 1.0f : 0.0f);
            hi[4]=(_Float16)bx.x; hi[5]=(_Float16)bx.y;
            hi[6]=(_Float16)bx.z; hi[7]=(_Float16)bx.w;
            char* dst = base + t * 32;
            *(f16x8*)dst        = lo;
            *(f16x8*)(dst + 16) = hi;
        }
    }

    // ---- W fragments (shared by both chains): wave wv, tile row m:
    //      unit u=8*(m>>2)+2*wv+(m&1), gate = tile*2 + ((m&3)>>1)
    f16x8 Wf[2][2];
    f32x4 bias4[2];
    #pragma unroll
    for (int tile = 0; tile < 2; ++tile) {
        int rm   = cidx & 3;
        int u    = 8 * (cidx >> 2) + 2 * wv + (rm & 1);
        int gate = tile * 2 + (rm >> 1);
        float scale = (gate == 2) ? TWO_LOG2E : -LOG2E;
        int n = gate * 32 + u;
        #pragma unroll
        for (int ks = 0; ks < 2; ++ks) {
            f16x8 v;
            #pragma unroll
            for (int jj = 0; jj < 8; ++jj) {
                int k = ks * 32 + quad * 8 + jj;
                float val = (k < 16) ? W_ih[n * 16 + k]
                          : (k >= 32) ? W_hh[n * 32 + (k - 32)]
                          : 0.0f;
                v[jj] = (_Float16)(val * scale);
            }
            Wf[tile][ks] = v;
        }
        #pragma unroll
        for (int r = 0; r < 4; ++r) {
            int ur = 8 * quad + 2 * wv + (r & 1);
            int gr = tile * 2 + (r >> 1);
            float sc = (gr == 2) ? TWO_LOG2E : -LOG2E;
            bias4[tile][r] = (b_ih[gr * 32 + ur] + b_hh[gr * 32 + ur]) * sc;
        }
    }

    // ---- addressing ----
    const bool qlow = (quad < 2);
    int xaddrA = qlow ? (0     + cidx * 1040 + quad * 16) : ZOFF;
    int xaddrB = qlow ? (16640 + cidx * 1040 + quad * 16) : ZOFF;
    const int xinc   = qlow ? 32 : 0;
    const int slot16 = lane << 4;                    // 16B gather slot
    const int wr_off = slot16 + (wv << 2);           // own dword within slot

    __syncthreads();   // staging visible

    // prime both chains: x[0] MFMAs (bias rides as C); h(0)=0
    f32x4 accpA[2], accpB[2];
    {
        f16x8 xfA = *(const f16x8*)(smem + xaddrA); xaddrA += xinc;
        f16x8 xfB = *(const f16x8*)(smem + xaddrB); xaddrB += xinc;
        #pragma unroll
        for (int tile = 0; tile < 2; ++tile) {
            accpA[tile] = __builtin_amdgcn_mfma_f32_16x16x32_f16(Wf[tile][0], xfA, bias4[tile], 0, 0, 0);
            accpB[tile] = __builtin_amdgcn_mfma_f32_16x16x32_f16(Wf[tile][0], xfB, bias4[tile], 0, 0, 0);
        }
    }

    union { int i[4]; f16x8 v; } hfA, hfB;
    hfA.i[0]=0; hfA.i[1]=0; hfA.i[2]=0; hfA.i[3]=0;
    hfB.i[0]=0; hfB.i[1]=0; hfB.i[2]=0; hfB.i[3]=0;
    const f32x2 one = {1.0f, 1.0f};
    f32x2 cstA = {0.0f, 0.0f}, cstB = {0.0f, 0.0f};
    f32x2 hvA = {0.0f, 0.0f}, hvB = {0.0f, 0.0f};

    #pragma unroll 2
    for (int t = 0; t < 32; ++t) {
        // h-MFMAs, both chains
        f32x4 aA0 = __builtin_amdgcn_mfma_f32_16x16x32_f16(Wf[0][1], hfA.v, accpA[0], 0, 0, 0);
        f32x4 aA1 = __builtin_amdgcn_mfma_f32_16x16x32_f16(Wf[1][1], hfA.v, accpA[1], 0, 0, 0);
        f32x4 aB0 = __builtin_amdgcn_mfma_f32_16x16x32_f16(Wf[0][1], hfB.v, accpB[0], 0, 0, 0);
        f32x4 aB1 = __builtin_amdgcn_mfma_f32_16x16x32_f16(Wf[1][1], hfB.v, accpB[1], 0, 0, 0);

        // prefetch next x (t=31 reads row pad — discarded)
        f16x8 xnA = *(const f16x8*)(smem + xaddrA); xaddrA += xinc;
        f16x8 xnB = *(const f16x8*)(smem + xaddrB); xaddrB += xinc;

        // activations, chain A then chain B (compiler interleaves the ladders)
        int pkA, pkB;
        {
            f32x2 Ei = {__builtin_amdgcn_exp2f(aA0[0]), __builtin_amdgcn_exp2f(aA0[1])};
            f32x2 Ef = {__builtin_amdgcn_exp2f(aA0[2]), __builtin_amdgcn_exp2f(aA0[3])};
            f32x2 Eg = {__builtin_amdgcn_exp2f(aA1[0]), __builtin_amdgcn_exp2f(aA1[1])};
            f32x2 Eo = {__builtin_amdgcn_exp2f(aA1[2]), __builtin_amdgcn_exp2f(aA1[3])};
            f32x2 t1  = Ei + one;
            f32x2 dig = t1 * Eg + t1;
            f32x2 tf  = Ef + one;
            f32x2 nn  = (Eg - one) * tf + cstA * dig;
            f32x2 den = tf * dig;
            f32x2 rde = {__builtin_amdgcn_rcpf(den.x), __builtin_amdgcn_rcpf(den.y)};
            f32x2 c   = nn * rde;
            cstA = c;
            f32x2 cl  = c * TWO_LOG2E;
            f32x2 Ec  = {__builtin_amdgcn_exp2f(cl.x), __builtin_amdgcn_exp2f(cl.y)};
            f32x2 to  = Eo + one;
            f32x2 dh  = to * Ec + to;
            f32x2 rdh = {__builtin_amdgcn_rcpf(dh.x), __builtin_amdgcn_rcpf(dh.y)};
            hvA = (Ec - one) * rdh;
            union { fp16x2 h; int i; } pku;
            pku.h = __builtin_amdgcn_cvt_pkrtz(hvA.x, hvA.y);
            pkA = pku.i;
        }
        {
            f32x2 Ei = {__builtin_amdgcn_exp2f(aB0[0]), __builtin_amdgcn_exp2f(aB0[1])};
            f32x2 Ef = {__builtin_amdgcn_exp2f(aB0[2]), __builtin_amdgcn_exp2f(aB0[3])};
            f32x2 Eg = {__builtin_amdgcn_exp2f(aB1[0]), __builtin_amdgcn_exp2f(aB1[1])};
            f32x2 Eo = {__builtin_amdgcn_exp2f(aB1[2]), __builtin_amdgcn_exp2f(aB1[3])};
            f32x2 t1  = Ei + one;
            f32x2 dig = t1 * Eg + t1;
            f32x2 tf  = Ef + one;
            f32x2 nn  = (Eg - one) * tf + cstB * dig;
            f32x2 den = tf * dig;
            f32x2 rde = {__builtin_amdgcn_rcpf(den.x), __builtin_amdgcn_rcpf(den.y)};
            f32x2 c   = nn * rde;
            cstB = c;
            f32x2 cl  = c * TWO_LOG2E;
            f32x2 Ec  = {__builtin_amdgcn_exp2f(cl.x), __builtin_amdgcn_exp2f(cl.y)};
            f32x2 to  = Eo + one;
            f32x2 dh  = to * Ec + to;
            f32x2 rdh = {__builtin_amdgcn_rcpf(dh.x), __builtin_amdgcn_rcpf(dh.y)};
            hvB = (Ec - one) * rdh;
            union { fp16x2 h; int i; } pku;
            pku.h = __builtin_amdgcn_cvt_pkrtz(hvB.x, hvB.y);
            pkB = pku.i;
        }

        // publish both chains' dwords; ONE barrier; gathers hide under x-MFMAs
        char* buf = smem + HXB + ((t & 1) ? 2048 : 0);
        *(int*)(buf + wr_off)        = pkA;
        *(int*)(buf + 1024 + wr_off) = pkB;
        __syncthreads();

        accpA[0] = __builtin_amdgcn_mfma_f32_16x16x32_f16(Wf[0][0], xnA, bias4[0], 0, 0, 0);
        accpA[1] = __builtin_amdgcn_mfma_f32_16x16x32_f16(Wf[1][0], xnA, bias4[1], 0, 0, 0);
        accpB[0] = __builtin_amdgcn_mfma_f32_16x16x32_f16(Wf[0][0], xnB, bias4[0], 0, 0, 0);
        accpB[1] = __builtin_amdgcn_mfma_f32_16x16x32_f16(Wf[1][0], xnB, bias4[1], 0, 0, 0);

        hfA.v = *(const f16x8*)(buf + slot16);
        hfB.v = *(const f16x8*)(buf + 1024 + slot16);
    }

    // ---- epilogue: fc2 on final h (fp32 via LDS scratch over X) ----
    __syncthreads();
    {
        int u0 = 8 * quad + 2 * wv;
        *(float2*)(smem +        cidx * 144 + u0 * 4) = (float2){hvA.x, hvA.y};
        *(float2*)(smem + 2304 + cidx * 144 + u0 * 4) = (float2){hvB.x, hvB.y};
    }
    __syncthreads();

    if (tid < 128) {
        int ch = tid >> 6, sub = tid & 63;
        int b = sub >> 2, jj = sub & 3;
        const float* fw   = fc2_W + jj * 32;
        const float* hrow = (const float*)(smem + ch * 2304 + b * 144);
        float s = fc2_b[jj];
        #pragma unroll
        for (int k = 0; k < 8; ++k) {
            float4 hvv = *(const float4*)(hrow + k * 4);
            s += fw[k*4+0] * hvv.x + fw[k*4+1] * hvv.y
               + fw[k*4+2] * hvv.z + fw[k*4+3] * hvv.w;
        }
        s = fminf(fmaxf(s, 0.0f), 1.0f);
        out[(long)blockIdx.x * 128 + tid] = s;
    }
}

extern "C" void kernel_launch(void* const* d_in, const int* in_sizes, int n_in,
                              void* d_out, int out_size, void* d_ws, size_t ws_size,
                              hipStream_t stream)
{
    // inputs: 0 objs(i32) 1 boxes(f32) 2 preds(i32) 3 subj(i32) 4 target(unused)
    //         5 obj_emb 6 pred_emb 7 W_ih 8 W_hh 9 b_ih 10 b_hh 11 fc2_W 12 fc2_b
    lstm_fused<<<1024, 256, LDS_BYTES, stream>>>(
        (const int*)d_in[0], (const float*)d_in[1], (const int*)d_in[2],
        (const int*)d_in[3],
        (const float*)d_in[5], (const float*)d_in[6],
        (const float*)d_in[7], (const float*)d_in[8],
        (const float*)d_in[9], (const float*)d_in[10],
        (const float*)d_in[11], (const float*)d_in[12],
        (float*)d_out);
}